// Round 7
// baseline (155.325 us; speedup 1.0000x reference)
//
#include <hip/hip_runtime.h>
#include <cstdint>

// Radius graph + per-atom top-K (K=32) nearest neighbors, per molecule.
// B=256 mols x n=512 atoms. Outputs concatenated float32 in d_out:
//   bond_i[E], bond_j[E], vec[E,3], dist[E], valid[E], E = N*K.
//
// R7: occupancy push + per-atom sort-suffix skipping.
//  - 128-thread blocks (2 waves, 32 atoms), grid 4096: LDS 9984 B/block ->
//    16 blocks/CU x 2 waves = 32 waves/CU static; finer dispatch granularity
//    (R3-R6 evidence: OccupancyPercent ~47% with 256-thread blocks)
//  - lane's 8 j-positions pinned in VGPRs (asm) -- no remat ds_reads
//  - cutoff: (d2_bits-1) <u 0x3F7FFFFF <=> 0 < d2 < 1, d2 via __f*_rn
//    (bit-identical to numpy) -> neighbor SET exact
//  - key = (d2_bits & ~511) | j; unsigned order == (trunc d2, j)
//  - 2 atoms per wave-iteration; ballot scatter-compact into wcA/wcB
//  - flip-form bitonic: 15-step 32-half prefix always; 6-step cross-half
//    suffix only when that atom/chunk has >32 live keys; 64-chunk
//    half-cleaner merge for C>64
//  - full-wave epilogue: bpermute B's slots to lanes 32..63; contiguous
//    64-lane stores, vec via dwordx3

#define K_NBR 32
#define MOL_N 512
#define CAP 240  // per-atom candidate cap; true max C <= ~180 for N(0,1)
typedef unsigned long long u64;
typedef unsigned u32;

#define DPPK(ctrl, v) __builtin_amdgcn_update_dpp(0, (v), (ctrl), 0xF, 0xF, true)
#define SWZK(off, v) __builtin_amdgcn_ds_swizzle((v), (off))

__device__ __forceinline__ int ce(int k, int o, bool up) {
  const u32 a = (u32)k, b = (u32)o;
  const u32 mn = a < b ? a : b;
  const u32 mx = a < b ? b : a;
  return (int)(up ? mx : mn);
}

struct LaneBits {
  bool b1, b2, b4, b8, b16, b32;
  int bp63;
};

// First 15 steps of the flip-form network: sorts EACH 32-lane half ascending.
__device__ __forceinline__ int bsort32_prefix(int k, const LaneBits& L) {
  k = ce(k, DPPK(0xB1, k), L.b1);    // S2  flip xor1
  k = ce(k, DPPK(0x1B, k), L.b2);    // S4  flip xor3
  k = ce(k, DPPK(0xB1, k), L.b1);    // S4  J1
  k = ce(k, DPPK(0x141, k), L.b4);   // S8  flip xor7 (row_half_mirror)
  k = ce(k, DPPK(0x4E, k), L.b2);    // S8  J2
  k = ce(k, DPPK(0xB1, k), L.b1);    // S8  J1
  k = ce(k, DPPK(0x140, k), L.b8);   // S16 flip xor15 (row_mirror)
  k = ce(k, SWZK(0x101F, k), L.b4);  // S16 J4
  k = ce(k, DPPK(0x4E, k), L.b2);    // S16 J2
  k = ce(k, DPPK(0xB1, k), L.b1);    // S16 J1
  k = ce(k, SWZK(0x7C1F, k), L.b16); // S32 flip xor31
  k = ce(k, DPPK(0x128, k), L.b8);   // S32 J8 (row_ror:8 == xor8)
  k = ce(k, SWZK(0x101F, k), L.b4);  // S32 J4
  k = ce(k, DPPK(0x4E, k), L.b2);    // S32 J2
  k = ce(k, DPPK(0xB1, k), L.b1);    // S32 J1
  return k;
}

// Remaining 6 steps: completes full sort-64 ascending across the wave.
__device__ __forceinline__ int bsort64_suffix(int k, const LaneBits& L) {
  k = ce(k, __builtin_amdgcn_ds_bpermute(L.bp63, k), L.b32);  // S64 flip xor63
  k = ce(k, SWZK(0x401F, k), L.b16); // S64 J16
  k = ce(k, DPPK(0x128, k), L.b8);   // S64 J8
  k = ce(k, SWZK(0x101F, k), L.b4);  // S64 J4
  k = ce(k, DPPK(0x4E, k), L.b2);    // S64 J2
  k = ce(k, DPPK(0xB1, k), L.b1);    // S64 J1
  return k;
}

// k, k2: ascending-sorted in lanes 0..31. Returns lowest-32 of the union,
// ascending in lanes 0..31 (bitonic half-cleaner).
__device__ __forceinline__ int merge_low32(int k, int k2, const LaneBits& L) {
  const int krev = SWZK(0x7C1F, k2);  // lane^31: reverse lanes 0..31
  const u32 a = (u32)k, b = (u32)krev;
  int m = (int)(a < b ? a : b);       // bitonic sequence of the 32 smallest
  m = ce(m, SWZK(0x401F, m), L.b16);
  m = ce(m, DPPK(0x128, m), L.b8);
  m = ce(m, SWZK(0x101F, m), L.b4);
  m = ce(m, DPPK(0x4E, m), L.b2);
  m = ce(m, DPPK(0xB1, m), L.b1);
  return m;
}

struct F3 { float x, y, z; };  // 12-B store -> global_store_dwordx3

__global__ __launch_bounds__(128, 8) void topo_kernel(
    const float* __restrict__ atoms_x, float* __restrict__ out, int E_i) {
  __shared__ float sx[MOL_N], sy[MOL_N], sz[MOL_N];
  __shared__ u32 cand[2][2][CAP];

  const int tid = threadIdx.x;
  const int lane = tid & 63;
  const int wave = tid >> 6;
  const int mol = blockIdx.x >> 4;   // 16 blocks per molecule
  const int blk = blockIdx.x & 15;   // 32 atoms per block
  const size_t E = (size_t)E_i;

  // ---- stage molecule positions into LDS (SoA), once ----
  const float* mp = atoms_x + (size_t)mol * (MOL_N * 3);
  for (int e = tid; e < MOL_N * 3; e += 128) {
    float v = mp[e];
    int a = e / 3;
    int c = e - a * 3;
    if (c == 0) sx[a] = v;
    else if (c == 1) sy[a] = v;
    else sz[a] = v;
  }
  __syncthreads();

  // ---- per-lane j-positions, pinned in VGPRs (defeats LDS remat) ----
  float px[8], py[8], pz[8];
#pragma unroll
  for (int s = 0; s < 8; ++s) {
    const int j = lane + (s << 6);
    px[s] = sx[j]; py[s] = sy[j]; pz[s] = sz[j];
  }
#pragma unroll
  for (int s = 0; s < 8; ++s) {
    asm volatile("" : "+v"(px[s]), "+v"(py[s]), "+v"(pz[s]));
  }

  float* o_bi = out;
  float* o_bj = out + E;
  float* o_vec = out + 2 * E;
  float* o_dist = out + 5 * E;
  float* o_val = out + 6 * E;

  u32* wcA = cand[wave][0];
  u32* wcB = cand[wave][1];
  LaneBits L;
  L.b1 = (lane & 1);  L.b2 = (lane & 2);   L.b4 = (lane & 4);
  L.b8 = (lane & 8);  L.b16 = (lane & 16); L.b32 = (lane & 32);
  L.bp63 = ((lane ^ 63) << 2);
  const int bpLo = (lane & 31) << 2;  // lanes 32..63 fetch lanes 0..31

  for (int it = 0; it < 8; ++it) {
    const int iA = blk * 32 + wave * 16 + (it << 1);  // atom pair (iA, iA+1)
    const int gA = mol * MOL_N + iA;                  // global idx of atom A
    const float xiA = sx[iA], yiA = sy[iA], ziA = sz[iA];
    const float xiB = sx[iA + 1], yiB = sy[iA + 1], ziB = sz[iA + 1];

    // ---- pass 1: exact d2 for both atoms, ballot scatter-compact ----
    int baseA = 0, baseB = 0;
#pragma unroll
    for (int s = 0; s < 8; ++s) {
      const u32 jj = (u32)(lane + (s << 6));
      const float dxA = __fsub_rn(px[s], xiA);
      const float dyA = __fsub_rn(py[s], yiA);
      const float dzA = __fsub_rn(pz[s], ziA);
      const float d2A = __fadd_rn(
          __fadd_rn(__fmul_rn(dxA, dxA), __fmul_rn(dyA, dyA)),
          __fmul_rn(dzA, dzA));
      const float dxB = __fsub_rn(px[s], xiB);
      const float dyB = __fsub_rn(py[s], yiB);
      const float dzB = __fsub_rn(pz[s], ziB);
      const float d2B = __fadd_rn(
          __fadd_rn(__fmul_rn(dxB, dxB), __fmul_rn(dyB, dyB)),
          __fmul_rn(dzB, dzB));
      const u32 dbA = __float_as_uint(d2A);
      const u32 dbB = __float_as_uint(d2B);
      const bool pA = (dbA - 1u) < 0x3F7FFFFFu;  // 0 < d2A < 1 (exact)
      const bool pB = (dbB - 1u) < 0x3F7FFFFFu;
      const u64 balA = __ballot(pA);
      const u64 balB = __ballot(pB);
      const int pfxA = (int)__builtin_amdgcn_mbcnt_hi(
          (u32)(balA >> 32), __builtin_amdgcn_mbcnt_lo((u32)balA, 0u));
      const int pfxB = (int)__builtin_amdgcn_mbcnt_hi(
          (u32)(balB >> 32), __builtin_amdgcn_mbcnt_lo((u32)balB, 0u));
      const int offA = baseA + pfxA;
      const int offB = baseB + pfxB;
      if (pA && offA < CAP) wcA[offA] = (dbA & 0xFFFFFE00u) | jj;
      if (pB && offB < CAP) wcB[offB] = (dbB & 0xFFFFFE00u) | jj;
      baseA += (int)__popcll(balA);
      baseB += (int)__popcll(balB);
    }
    const int CA = baseA < CAP ? baseA : CAP;  // wave-uniform
    const int CB = baseB < CAP ? baseB : CAP;
    __builtin_amdgcn_wave_barrier();  // pin LDS op order (in-order DS pipe)

    // ---- two interleaved top-32 sorts, per-atom suffix skipping ----
    int kA = (lane < CA) ? (int)wcA[lane] : (int)0xFFFFFFFFu;
    int kB = (lane < CB) ? (int)wcB[lane] : (int)0xFFFFFFFFu;
    kA = bsort32_prefix(kA, L);
    kB = bsort32_prefix(kB, L);
    if (CA > 32) kA = bsort64_suffix(kA, L);
    if (CB > 32) kB = bsort64_suffix(kB, L);
    const int Cm = CA > CB ? CA : CB;
    for (int b0 = 64; b0 < Cm; b0 += 64) {  // wave-uniform trip count
      if (b0 < CA) {
        int k2 = (b0 + lane < CA) ? (int)wcA[b0 + lane] : (int)0xFFFFFFFFu;
        k2 = bsort32_prefix(k2, L);
        if (CA - b0 > 32) k2 = bsort64_suffix(k2, L);
        kA = merge_low32(kA, k2, L);
      }
      if (b0 < CB) {
        int k2 = (b0 + lane < CB) ? (int)wcB[b0 + lane] : (int)0xFFFFFFFFu;
        k2 = bsort32_prefix(k2, L);
        if (CB - b0 > 32) k2 = bsort64_suffix(k2, L);
        kB = merge_low32(kB, k2, L);
      }
    }
    __builtin_amdgcn_wave_barrier();  // reads done before next scatter

    // ---- full-wave epilogue: A in lanes 0..31, B in lanes 32..63 ----
    const int kBm = __builtin_amdgcn_ds_bpermute(bpLo, kB);
    const u32 key = (u32)(L.b32 ? kBm : kA);
    const bool valid = (key != 0xFFFFFFFFu);
    const int i_loc = iA + (lane >> 5);
    const int j = (int)(key & 511u);
    const int js = valid ? j : i_loc;  // self -> vec = exact 0
    const float xi = L.b32 ? xiB : xiA;
    const float yi = L.b32 ? yiB : yiA;
    const float zi = L.b32 ? ziB : ziA;
    const float vx = __fsub_rn(sx[js], xi);
    const float vy = __fsub_rn(sy[js], yi);
    const float vz = __fsub_rn(sz[js], zi);
    const float d2t = __uint_as_float(key & 0xFFFFFE00u);
    const float dist = __builtin_amdgcn_sqrtf(d2t);
    const size_t e = (size_t)gA * K_NBR + (size_t)lane;  // contiguous 64
    o_bi[e] = valid ? (float)(gA + (lane >> 5)) : -1.0f;
    o_bj[e] = valid ? (float)(mol * MOL_N + j) : -1.0f;
    F3 v3;
    v3.x = valid ? vx : 0.0f;
    v3.y = valid ? vy : 0.0f;
    v3.z = valid ? vz : 0.0f;
    ((F3*)o_vec)[e] = v3;
    o_dist[e] = valid ? dist : 0.0f;
    o_val[e] = valid ? 1.0f : 0.0f;
  }
}

extern "C" void kernel_launch(void* const* d_in, const int* in_sizes, int n_in,
                              void* d_out, int out_size, void* d_ws,
                              size_t ws_size, hipStream_t stream) {
  const float* atoms_x = (const float*)d_in[0];
  const int N = in_sizes[0] / 3;  // 131072 atoms
  const int E = out_size / 7;     // N * K
  const int blocks = N / 32;      // 32 atoms per block (2 waves x 16 atoms)
  topo_kernel<<<blocks, 128, 0, stream>>>(atoms_x, (float*)d_out, E);
}